// Round 6
// baseline (1306.252 us; speedup 1.0000x reference)
//
#include <hip/hip_runtime.h>
#include <hip/hip_bf16.h>

// ---------------------------------------------------------------------------
// GCN link predictor, R6: bucketed CSR build + bf16 z + MFMA GEMMs.
// R5 post-mortem: decode 96us (819MB f32 z-gathers), CSR build ~130us hidden
// (random 4B csr scatter -> ~105MB write amplification, R3 evidence).
// Changes: (1) z stored bf16 (gather traffic halved, table 6.4MB);
// (2) CSR built via 196 node-contiguous buckets: partition pass with
// per-bucket atomic cursors (coalesced 8B pair writes), then per-bucket LDS
// counting sort (csr stores land in a 32KB window -> no write amplification).
// Output: FLOAT32 [logits(2E)][edge row0(2E)][row1(2E)] (established R2).
// ---------------------------------------------------------------------------

#define IN_F  128
#define HID_F 64
#define OUT_F 32
#define BKT_SH 9                 // 512 nodes per bucket
#define BKT_SZ 512

// workspace element offsets (4-byte units); N=100000, E=1600000; 58.8 MB total
#define OFF_CNT     0            // N ints
#define OFF_FLAGS   100000       // 2 ints
#define OFF_BSUMS   100064       // 128 ints
#define OFF_W1T     100256       // 8192 bf16 = 4096 ints
#define OFF_W2T     104352       // 2048 bf16 = 1024 ints
#define OFF_ROWP    105600       // N+1 ints
#define OFF_BKTCUR  205664       // 256 ints
#define OFF_DINV    206000       // N floats
#define OFF_EPAIRS  306000       // 2E ints (src,dst pairs) -> 3506000
#define OFF_CSR     3506000      // E ints -> 5106000
#define OFF_XW1     5106000      // N*64 bf16 -> 8306000
#define OFF_H       8306000      // N*64 bf16 -> 11506000
#define OFF_XW2     11506000     // N*32 bf16 -> 13106000
#define OFF_Z       13106000     // N*32 bf16 -> 14706000

typedef short short8 __attribute__((ext_vector_type(8)));
typedef float f32x4  __attribute__((ext_vector_type(4)));
typedef unsigned short bfx8 __attribute__((ext_vector_type(8)));
typedef unsigned short bfx4 __attribute__((ext_vector_type(4)));

__device__ __forceinline__ float ldf(const void* p, int i, int f32) {
  if (f32) return ((const float*)p)[i];
  unsigned int w = ((unsigned int)((const unsigned short*)p)[i]) << 16;
  return __uint_as_float(w);
}
__device__ __forceinline__ int ldi(const void* p, long long i, int i64) {
  if (i64) return (int)((const long long*)p)[i];
  return ((const int*)p)[i];
}
__device__ __forceinline__ int clampN(int v, int N) {
  unsigned u = (unsigned)v;
  return (u < (unsigned)N) ? v : 0;
}
__device__ __forceinline__ unsigned short f2bf(float f) {   // RNE f32->bf16
  unsigned u = __float_as_uint(f);
  return (unsigned short)((u + 0x7FFFu + ((u >> 16) & 1u)) >> 16);
}
__device__ __forceinline__ float bf2f(unsigned short h) {
  return __uint_as_float(((unsigned)h) << 16);
}

// --- prep: detect dtypes + transpose weights (block 0); zero cnt (rest) ----
__global__ __launch_bounds__(256) void k_prep(const void* __restrict__ x,
                                              const void* __restrict__ pe,
                                              const void* __restrict__ W1,
                                              const void* __restrict__ W2,
                                              int* __restrict__ flags,
                                              unsigned short* __restrict__ w1t,
                                              unsigned short* __restrict__ w2t,
                                              int* __restrict__ cnt, int N) {
  if (blockIdx.x > 0) {
    int v = (blockIdx.x - 1) * 256 + threadIdx.x;
    if (v < N) cnt[v] = 0;
    return;
  }
  __shared__ int s_big, s_nzodd;
  int t = threadIdx.x;
  if (t == 0) { s_big = 0; s_nzodd = 0; }
  __syncthreads();
  int nbig = 0, nz = 0;
  const unsigned short* xb = (const unsigned short*)x;
  for (int i = t; i < 4096; i += 256) {
    int ex = (xb[i] >> 7) & 0xFF;
    if (ex >= 147) nbig++;               // |v|>=2^20 impossible for N(0,1) bf16
  }
  const int* pi = (const int*)pe;
  for (int i = t; i < 2048; i += 256) {
    if (pi[2 * i + 1] != 0) nz++;        // int64 hi-words all zero
  }
  atomicAdd(&s_big, nbig);
  atomicAdd(&s_nzodd, nz);
  __syncthreads();
  int f32 = (s_big > 400) ? 1 : 0;
  if (t == 0) {
    flags[0] = f32;
    flags[1] = (s_nzodd < 100) ? 1 : 0;
  }
  for (int i = t; i < HID_F * IN_F; i += 256) {   // W1T[n*128+k] = W1[k*64+n]
    int n = i >> 7, k = i & 127;
    w1t[i] = f2bf(ldf(W1, k * HID_F + n, f32));
  }
  for (int i = t; i < OUT_F * HID_F; i += 256) {  // W2T[n*64+k] = W2[k*32+n]
    int n = i >> 6, k = i & 63;
    w2t[i] = f2bf(ldf(W2, k * OUT_F + n, f32));
  }
}

// --- degree count ----------------------------------------------------------
__global__ __launch_bounds__(256) void k_count(const void* __restrict__ pe,
                                               int* __restrict__ cnt,
                                               const int* __restrict__ flags,
                                               int E, int N) {
  int e = blockIdx.x * 256 + threadIdx.x;
  if (e >= E) return;
  int col = clampN(ldi(pe, (long long)E + e, flags[1]), N);
  atomicAdd(&cnt[col], 1);
}
__global__ __launch_bounds__(256) void k_dinv(const int* __restrict__ cnt,
                                              float* __restrict__ dinv, int N) {
  int v = blockIdx.x * 256 + threadIdx.x;
  if (v < N) dinv[v] = 1.0f / sqrtf((float)(cnt[v] + 1));  // +1 self loop
}

// --- prefix scan (3 kernels, 1024 elems/block) -----------------------------
__global__ __launch_bounds__(256) void k_bsum(const int* __restrict__ cnt,
                                              int* __restrict__ bsums, int N) {
  __shared__ int sd[256];
  int b = blockIdx.x, t = threadIdx.x;
  int base = b * 1024 + t * 4;
  int s = 0;
#pragma unroll
  for (int k = 0; k < 4; ++k) if (base + k < N) s += cnt[base + k];
  sd[t] = s;
  __syncthreads();
  for (int off = 128; off > 0; off >>= 1) {
    if (t < off) sd[t] += sd[t + off];
    __syncthreads();
  }
  if (t == 0) bsums[b] = sd[0];
}
__global__ void k_scan_bsums(int* __restrict__ bsums, int B) {
  if (threadIdx.x == 0 && blockIdx.x == 0) {
    int run = 0;
    for (int i = 0; i < B; ++i) { int v = bsums[i]; bsums[i] = run; run += v; }
    bsums[B] = run;
  }
}
__global__ __launch_bounds__(256) void k_scan_apply(const int* __restrict__ cnt,
                                                    const int* __restrict__ bsums,
                                                    int* __restrict__ row_ptr,
                                                    int N, int B) {
  __shared__ int sd[256];
  int b = blockIdx.x, t = threadIdx.x;
  int base = b * 1024 + t * 4;
  int v[4]; int s = 0;
#pragma unroll
  for (int k = 0; k < 4; ++k) { v[k] = (base + k < N) ? cnt[base + k] : 0; s += v[k]; }
  sd[t] = s;
  __syncthreads();
  for (int off = 1; off < 256; off <<= 1) {      // Hillis-Steele inclusive
    int tmp = (t >= off) ? sd[t - off] : 0;
    __syncthreads();
    sd[t] += tmp;
    __syncthreads();
  }
  int gbase = bsums[b] + sd[t] - s;
#pragma unroll
  for (int k = 0; k < 4; ++k) {
    if (base + k < N) { row_ptr[base + k] = gbase; gbase += v[k]; }
  }
  if (b == 0 && t == 0) row_ptr[N] = bsums[B];
}
__global__ void k_initcur(const int* __restrict__ row_ptr,
                          int* __restrict__ bktcur, int NB, int N) {
  int b = threadIdx.x;
  if (b < NB) bktcur[b] = row_ptr[min(b << BKT_SH, N)];
}

// --- partition edges into node-contiguous buckets (coalescing-friendly) ----
__global__ __launch_bounds__(256) void k_part(const void* __restrict__ pe,
                                              int* __restrict__ bktcur,
                                              int2* __restrict__ epairs,
                                              const int* __restrict__ flags,
                                              int E, int N) {
  int e = blockIdx.x * 256 + threadIdx.x;
  if (e >= E) return;
  int i64 = flags[1];
  int src = clampN(ldi(pe, e, i64), N);
  int dst = clampN(ldi(pe, (long long)E + e, i64), N);
  int pos = atomicAdd(&bktcur[dst >> BKT_SH], 1);  // consecutive slots coalesce
  epairs[pos] = make_int2(src, dst);
}

// --- per-bucket LDS counting sort -> csr (stores confined to ~32KB window) -
__global__ __launch_bounds__(256) void k_build(const int* __restrict__ row_ptr,
                                               const int2* __restrict__ epairs,
                                               int* __restrict__ csr_src,
                                               int N) {
  __shared__ int cur[BKT_SZ];
  int b = blockIdx.x, t = threadIdx.x;
  int node0 = b << BKT_SH;
  int nend = min(node0 + BKT_SZ, N);
  for (int i = t; i < nend - node0; i += 256) cur[i] = row_ptr[node0 + i];
  __syncthreads();
  int estart = row_ptr[node0], eend = row_ptr[nend];
  for (int j = estart + t; j < eend; j += 256) {
    int2 p = epairs[j];
    int pos = atomicAdd(&cur[p.y - node0], 1);
    csr_src[pos] = p.x;
  }
}

// --- gemm1 (MFMA): xw1 = x @ W1, bf16 out ----------------------------------
// wave: 16 rows x 64 cols. A[m=lane&15][k=quad*8+j]; C/D col=lane&15,
// row=quad*4+reg (verified m89).
__global__ __launch_bounds__(256) void k_gemm1(const void* __restrict__ x,
                                               const unsigned short* __restrict__ w1t,
                                               unsigned short* __restrict__ xw1,
                                               const int* __restrict__ flags, int N) {
  int w = threadIdx.x >> 6, lane = threadIdx.x & 63;
  int m = lane & 15, quad = lane >> 4;
  int r0 = blockIdx.x * 64 + w * 16;
  int rr = r0 + m; if (rr >= N) rr = N - 1;
  int f32 = flags[0];
  short8 A[4];
  if (f32) {
    const float* xf = (const float*)x + (size_t)rr * IN_F;
#pragma unroll
    for (int ks = 0; ks < 4; ++ks) {
      const float* p = xf + ks * 32 + quad * 8;
      short8 a;
#pragma unroll
      for (int j = 0; j < 8; ++j) a[j] = (short)f2bf(p[j]);
      A[ks] = a;
    }
  } else {
    const unsigned short* xb = (const unsigned short*)x + (size_t)rr * IN_F;
#pragma unroll
    for (int ks = 0; ks < 4; ++ks)
      A[ks] = *(const short8*)(xb + ks * 32 + quad * 8);
  }
#pragma unroll
  for (int nt = 0; nt < 4; ++nt) {
    f32x4 acc = {0.f, 0.f, 0.f, 0.f};
#pragma unroll
    for (int ks = 0; ks < 4; ++ks) {
      short8 Bf = *(const short8*)(w1t + (nt * 16 + m) * IN_F + ks * 32 + quad * 8);
      acc = __builtin_amdgcn_mfma_f32_16x16x32_bf16(A[ks], Bf, acc, 0, 0, 0);
    }
#pragma unroll
    for (int reg = 0; reg < 4; ++reg) {
      int row = r0 + quad * 4 + reg;
      if (row < N) xw1[(size_t)row * HID_F + nt * 16 + m] = f2bf(acc[reg]);
    }
  }
}

// --- gather1: h = relu(b1 + dv*(dv*xw1[v] + sum dinv[s]*xw1[s])), bf16 out -
__global__ __launch_bounds__(256) void k_gather1(const int* __restrict__ row_ptr,
                                                 const int* __restrict__ csr_src,
                                                 const float* __restrict__ dinv,
                                                 const unsigned short* __restrict__ xw1,
                                                 const void* __restrict__ b1,
                                                 unsigned short* __restrict__ h,
                                                 const int* __restrict__ flags, int N) {
  int v = blockIdx.x * 4 + (threadIdx.x >> 6);
  if (v >= N) return;
  int lane = threadIdx.x & 63;
  int sub = lane >> 3, l8 = lane & 7;
  int start = row_ptr[v], end = row_ptr[v + 1];
  float a[8] = {0.f,0.f,0.f,0.f,0.f,0.f,0.f,0.f};
  for (int j = start + sub; j < end; j += 8) {
    int s = csr_src[j];
    float ds = dinv[s];
    bfx8 wv = *(const bfx8*)(xw1 + (size_t)s * HID_F + l8 * 8);
#pragma unroll
    for (int q = 0; q < 8; ++q) a[q] += ds * bf2f(wv[q]);
  }
#pragma unroll
  for (int q = 0; q < 8; ++q) {
    a[q] += __shfl_xor(a[q], 8);
    a[q] += __shfl_xor(a[q], 16);
    a[q] += __shfl_xor(a[q], 32);
  }
  if (sub == 0) {
    float dv = dinv[v];
    bfx8 sw = *(const bfx8*)(xw1 + (size_t)v * HID_F + l8 * 8);
    int f32 = flags[0];
    bfx8 r;
#pragma unroll
    for (int q = 0; q < 8; ++q) {
      float val = ldf(b1, l8 * 8 + q, f32) + dv * (dv * bf2f(sw[q]) + a[q]);
      r[q] = f2bf(fmaxf(val, 0.f));
    }
    *(bfx8*)(h + (size_t)v * HID_F + l8 * 8) = r;
  }
}

// --- gemm2 (MFMA): xw2 = h @ W2, bf16 out ----------------------------------
__global__ __launch_bounds__(256) void k_gemm2(const unsigned short* __restrict__ h,
                                               const unsigned short* __restrict__ w2t,
                                               unsigned short* __restrict__ xw2, int N) {
  int w = threadIdx.x >> 6, lane = threadIdx.x & 63;
  int m = lane & 15, quad = lane >> 4;
  int r0 = blockIdx.x * 64 + w * 16;
  int rr = r0 + m; if (rr >= N) rr = N - 1;
  const unsigned short* hb = h + (size_t)rr * HID_F;
  short8 A[2];
#pragma unroll
  for (int ks = 0; ks < 2; ++ks)
    A[ks] = *(const short8*)(hb + ks * 32 + quad * 8);
#pragma unroll
  for (int nt = 0; nt < 2; ++nt) {
    f32x4 acc = {0.f, 0.f, 0.f, 0.f};
#pragma unroll
    for (int ks = 0; ks < 2; ++ks) {
      short8 Bf = *(const short8*)(w2t + (nt * 16 + m) * HID_F + ks * 32 + quad * 8);
      acc = __builtin_amdgcn_mfma_f32_16x16x32_bf16(A[ks], Bf, acc, 0, 0, 0);
    }
#pragma unroll
    for (int reg = 0; reg < 4; ++reg) {
      int row = r0 + quad * 4 + reg;
      if (row < N) xw2[(size_t)row * OUT_F + nt * 16 + m] = f2bf(acc[reg]);
    }
  }
}

// --- gather2: z = b2 + dv*(dv*xw2[v] + sum dinv[s]*xw2[s]), bf16 out -------
__global__ __launch_bounds__(256) void k_gather2(const int* __restrict__ row_ptr,
                                                 const int* __restrict__ csr_src,
                                                 const float* __restrict__ dinv,
                                                 const unsigned short* __restrict__ xw2,
                                                 const void* __restrict__ b2,
                                                 unsigned short* __restrict__ z,
                                                 const int* __restrict__ flags, int N) {
  int v = blockIdx.x * 4 + (threadIdx.x >> 6);
  if (v >= N) return;
  int lane = threadIdx.x & 63;
  int sub = lane >> 3, l8 = lane & 7;
  int start = row_ptr[v], end = row_ptr[v + 1];
  float a[4] = {0.f, 0.f, 0.f, 0.f};
  for (int j = start + sub; j < end; j += 8) {
    int s = csr_src[j];
    float ds = dinv[s];
    bfx4 wv = *(const bfx4*)(xw2 + (size_t)s * OUT_F + l8 * 4);
#pragma unroll
    for (int q = 0; q < 4; ++q) a[q] += ds * bf2f(wv[q]);
  }
#pragma unroll
  for (int q = 0; q < 4; ++q) {
    a[q] += __shfl_xor(a[q], 8);
    a[q] += __shfl_xor(a[q], 16);
    a[q] += __shfl_xor(a[q], 32);
  }
  if (sub == 0) {
    float dv = dinv[v];
    bfx4 sw = *(const bfx4*)(xw2 + (size_t)v * OUT_F + l8 * 4);
    int f32 = flags[0];
    bfx4 r;
#pragma unroll
    for (int q = 0; q < 4; ++q)
      r[q] = f2bf(ldf(b2, l8 * 4 + q, f32) + dv * (dv * bf2f(sw[q]) + a[q]));
    *(bfx4*)(z + (size_t)v * OUT_F + l8 * 4) = r;
  }
}

// --- decode + edge copy: 4 lanes/edge, bf16 z, f32 accumulate --------------
__global__ __launch_bounds__(256) void k_decode(const void* __restrict__ pe,
                                                const void* __restrict__ ne,
                                                const unsigned short* __restrict__ z,
                                                float* __restrict__ out,
                                                const int* __restrict__ flags,
                                                int E, int N) {
  int tid = blockIdx.x * 256 + threadIdx.x;
  int e = tid >> 2, g = tid & 3;
  int twoE = 2 * E;
  if (e >= twoE) return;
  int i64 = flags[1];
  int src, dst;
  if (e < E) { src = ldi(pe, e, i64); dst = ldi(pe, (long long)E + e, i64); }
  else       { src = ldi(ne, e - E, i64); dst = ldi(ne, e, i64); }
  if (g == 1) out[twoE + e] = (float)src;        // edge row0 passthrough
  if (g == 2) out[2 * twoE + e] = (float)dst;    // edge row1 passthrough
  int cs = clampN(src, N), cd = clampN(dst, N);
  bfx8 a = *(const bfx8*)(z + (size_t)cs * OUT_F + g * 8);
  bfx8 b = *(const bfx8*)(z + (size_t)cd * OUT_F + g * 8);
  float s = 0.f;
#pragma unroll
  for (int q = 0; q < 8; ++q) s += bf2f(a[q]) * bf2f(b[q]);
  s += __shfl_xor(s, 1);
  s += __shfl_xor(s, 2);
  s = fminf(fmaxf(s, -500.0f), 500.0f);          // insurance rail (R2 notes)
  if (g == 0) out[e] = s;
}

extern "C" void kernel_launch(void* const* d_in, const int* in_sizes, int n_in,
                              void* d_out, int out_size, void* d_ws, size_t ws_size,
                              hipStream_t stream) {
  const void* x  = d_in[0];
  const void* W1 = d_in[1];
  const void* b1 = d_in[2];
  const void* W2 = d_in[3];
  const void* b2 = d_in[4];
  const void* pe = d_in[5];
  const void* ne = d_in[6];
  int N = in_sizes[0] / IN_F;       // 100000
  int E = in_sizes[5] / 2;          // 1600000
  int B = (N + 1023) / 1024;        // 98
  int NB = (N + BKT_SZ - 1) / BKT_SZ; // 196

  int*   ip    = (int*)d_ws;
  float* ws    = (float*)d_ws;
  int*   cnt   = ip + OFF_CNT;
  int*   flags = ip + OFF_FLAGS;
  int*   bsums = ip + OFF_BSUMS;
  unsigned short* w1t = (unsigned short*)(ip + OFF_W1T);
  unsigned short* w2t = (unsigned short*)(ip + OFF_W2T);
  int*   rowp  = ip + OFF_ROWP;
  int*   bktcur= ip + OFF_BKTCUR;
  float* dinv  = ws + OFF_DINV;
  int2*  epairs= (int2*)(ip + OFF_EPAIRS);
  int*   csr   = ip + OFF_CSR;
  unsigned short* xw1 = (unsigned short*)(ip + OFF_XW1);
  unsigned short* h   = (unsigned short*)(ip + OFF_H);
  unsigned short* xw2 = (unsigned short*)(ip + OFF_XW2);
  unsigned short* zz  = (unsigned short*)(ip + OFF_Z);
  float* out   = (float*)d_out;

  k_prep<<<1 + (N + 255) / 256, 256, 0, stream>>>(x, pe, W1, W2, flags, w1t, w2t, cnt, N);
  k_count<<<(E + 255) / 256, 256, 0, stream>>>(pe, cnt, flags, E, N);
  k_dinv<<<(N + 255) / 256, 256, 0, stream>>>(cnt, dinv, N);
  k_bsum<<<B, 256, 0, stream>>>(cnt, bsums, N);
  k_scan_bsums<<<1, 64, 0, stream>>>(bsums, B);
  k_scan_apply<<<B, 256, 0, stream>>>(cnt, bsums, rowp, N, B);
  k_initcur<<<1, 256, 0, stream>>>(rowp, bktcur, NB, N);
  k_part<<<(E + 255) / 256, 256, 0, stream>>>(pe, bktcur, epairs, flags, E, N);
  k_build<<<NB, 256, 0, stream>>>(rowp, epairs, csr, N);
  k_gemm1<<<(N + 63) / 64, 256, 0, stream>>>(x, w1t, xw1, flags, N);
  k_gather1<<<(N + 3) / 4, 256, 0, stream>>>(rowp, csr, dinv, xw1, b1, h, flags, N);
  k_gemm2<<<(N + 63) / 64, 256, 0, stream>>>(h, w2t, xw2, N);
  k_gather2<<<(N + 3) / 4, 256, 0, stream>>>(rowp, csr, dinv, xw2, b2, zz, flags, N);
  k_decode<<<(2 * E * 4 + 255) / 256, 256, 0, stream>>>(pe, ne, zz, out, flags, E, N);
}

// Round 7
// 425.775 us; speedup vs baseline: 3.0679x; 3.0679x over previous
//
#include <hip/hip_runtime.h>
#include <hip/hip_bf16.h>

// ---------------------------------------------------------------------------
// GCN link predictor, R7: R5 CSR build (low-contention atomics) + R6 bf16 z.
// R6 post-mortem: 196 bucket cursors -> same-address atomic serialization
// (~110ns x 8.2k per address = 895us in k_part). R5's countslot (100k
// addresses, ~16 atomics each) was never the bottleneck — reverted to it.
// Kept from R6: bf16 z table (decode gather traffic halved vs f32).
//   h = relu(b1 + dv*(dv*xw1[v] + sum dinv[s]*xw1[s])),  xw1 = x @ W1 (MFMA)
//   z = b2 + dv*(dv*xw2[v] + sum dinv[s]*xw2[s]),        xw2 = h @ W2 (MFMA)
//   logits[e] = dot(z[src], z[dst]) over [pos; neg]
// Output: FLOAT32 [logits(2E)][edge row0(2E)][row1(2E)] (established R2).
// ---------------------------------------------------------------------------

#define IN_F  128
#define HID_F 64
#define OUT_F 32

// workspace element offsets (4-byte units); N=100000, E=1600000
#define OFF_CNT     0            // N ints
#define OFF_FLAGS   100000       // 2 ints
#define OFF_BSUMS   100064       // 128 ints
#define OFF_W1T     100256       // 8192 bf16 = 4096 ints
#define OFF_W2T     104352       // 2048 bf16 = 1024 ints
#define OFF_ROWP    105600       // N+1 ints
#define OFF_DINV    206000       // N floats
#define OFF_SLOT    306000       // E ints -> 1906000
#define OFF_CSR     1906000      // E ints -> 3506000
#define OFF_XW1     3506000      // N*64 bf16 -> 6706000
#define OFF_H       6706000      // N*64 bf16 -> 9906000
#define OFF_XW2     9906000      // N*32 bf16 -> 11506000
#define OFF_Z       11506000     // N*32 bf16 -> 13106000 (52.4 MB total)

typedef short short8 __attribute__((ext_vector_type(8)));
typedef float f32x4  __attribute__((ext_vector_type(4)));
typedef unsigned short bfx8 __attribute__((ext_vector_type(8)));
typedef unsigned short bfx4 __attribute__((ext_vector_type(4)));

__device__ __forceinline__ float ldf(const void* p, int i, int f32) {
  if (f32) return ((const float*)p)[i];
  unsigned int w = ((unsigned int)((const unsigned short*)p)[i]) << 16;
  return __uint_as_float(w);
}
__device__ __forceinline__ int ldi(const void* p, long long i, int i64) {
  if (i64) return (int)((const long long*)p)[i];
  return ((const int*)p)[i];
}
__device__ __forceinline__ int clampN(int v, int N) {
  unsigned u = (unsigned)v;
  return (u < (unsigned)N) ? v : 0;
}
__device__ __forceinline__ unsigned short f2bf(float f) {   // RNE f32->bf16
  unsigned u = __float_as_uint(f);
  return (unsigned short)((u + 0x7FFFu + ((u >> 16) & 1u)) >> 16);
}
__device__ __forceinline__ float bf2f(unsigned short h) {
  return __uint_as_float(((unsigned)h) << 16);
}

// --- prep: detect dtypes + transpose weights (block 0); zero cnt (rest) ----
__global__ __launch_bounds__(256) void k_prep(const void* __restrict__ x,
                                              const void* __restrict__ pe,
                                              const void* __restrict__ W1,
                                              const void* __restrict__ W2,
                                              int* __restrict__ flags,
                                              unsigned short* __restrict__ w1t,
                                              unsigned short* __restrict__ w2t,
                                              int* __restrict__ cnt, int N) {
  if (blockIdx.x > 0) {
    int v = (blockIdx.x - 1) * 256 + threadIdx.x;
    if (v < N) cnt[v] = 0;
    return;
  }
  __shared__ int s_big, s_nzodd;
  int t = threadIdx.x;
  if (t == 0) { s_big = 0; s_nzodd = 0; }
  __syncthreads();
  int nbig = 0, nz = 0;
  const unsigned short* xb = (const unsigned short*)x;
  for (int i = t; i < 4096; i += 256) {
    int ex = (xb[i] >> 7) & 0xFF;
    if (ex >= 147) nbig++;               // |v|>=2^20 impossible for N(0,1) bf16
  }
  const int* pi = (const int*)pe;
  for (int i = t; i < 2048; i += 256) {
    if (pi[2 * i + 1] != 0) nz++;        // int64 hi-words all zero
  }
  atomicAdd(&s_big, nbig);
  atomicAdd(&s_nzodd, nz);
  __syncthreads();
  int f32 = (s_big > 400) ? 1 : 0;
  if (t == 0) {
    flags[0] = f32;
    flags[1] = (s_nzodd < 100) ? 1 : 0;
  }
  for (int i = t; i < HID_F * IN_F; i += 256) {   // W1T[n*128+k] = W1[k*64+n]
    int n = i >> 7, k = i & 127;
    w1t[i] = f2bf(ldf(W1, k * HID_F + n, f32));
  }
  for (int i = t; i < OUT_F * HID_F; i += 256) {  // W2T[n*64+k] = W2[k*32+n]
    int n = i >> 6, k = i & 63;
    w2t[i] = f2bf(ldf(W2, k * OUT_F + n, f32));
  }
}

// --- degree count + slot assignment (100k-address atomics: low contention) -
__global__ __launch_bounds__(256) void k_countslot(const void* __restrict__ pe,
                                                   int* __restrict__ cnt,
                                                   int* __restrict__ slot,
                                                   const int* __restrict__ flags,
                                                   int E, int N) {
  int e = blockIdx.x * 256 + threadIdx.x;
  if (e >= E) return;
  int col = clampN(ldi(pe, (long long)E + e, flags[1]), N);
  slot[e] = atomicAdd(&cnt[col], 1);
}

// --- prefix scan (3 kernels, 1024 elems/block); scan_apply also emits dinv -
__global__ __launch_bounds__(256) void k_bsum(const int* __restrict__ cnt,
                                              int* __restrict__ bsums, int N) {
  __shared__ int sd[256];
  int b = blockIdx.x, t = threadIdx.x;
  int base = b * 1024 + t * 4;
  int s = 0;
#pragma unroll
  for (int k = 0; k < 4; ++k) if (base + k < N) s += cnt[base + k];
  sd[t] = s;
  __syncthreads();
  for (int off = 128; off > 0; off >>= 1) {
    if (t < off) sd[t] += sd[t + off];
    __syncthreads();
  }
  if (t == 0) bsums[b] = sd[0];
}
__global__ void k_scan_bsums(int* __restrict__ bsums, int B) {
  if (threadIdx.x == 0 && blockIdx.x == 0) {
    int run = 0;
    for (int i = 0; i < B; ++i) { int v = bsums[i]; bsums[i] = run; run += v; }
    bsums[B] = run;
  }
}
__global__ __launch_bounds__(256) void k_scan_apply(const int* __restrict__ cnt,
                                                    const int* __restrict__ bsums,
                                                    int* __restrict__ row_ptr,
                                                    float* __restrict__ dinv,
                                                    int N, int B) {
  __shared__ int sd[256];
  int b = blockIdx.x, t = threadIdx.x;
  int base = b * 1024 + t * 4;
  int v[4]; int s = 0;
#pragma unroll
  for (int k = 0; k < 4; ++k) { v[k] = (base + k < N) ? cnt[base + k] : 0; s += v[k]; }
  sd[t] = s;
  __syncthreads();
  for (int off = 1; off < 256; off <<= 1) {      // Hillis-Steele inclusive
    int tmp = (t >= off) ? sd[t - off] : 0;
    __syncthreads();
    sd[t] += tmp;
    __syncthreads();
  }
  int gbase = bsums[b] + sd[t] - s;
#pragma unroll
  for (int k = 0; k < 4; ++k) {
    if (base + k < N) {
      row_ptr[base + k] = gbase; gbase += v[k];
      dinv[base + k] = 1.0f / sqrtf((float)(v[k] + 1));   // +1 self loop
    }
  }
  if (b == 0 && t == 0) row_ptr[N] = bsums[B];
}

// --- CSR fill (no atomics: slot precomputed) -------------------------------
__global__ __launch_bounds__(256) void k_fill(const void* __restrict__ pe,
                                              const int* __restrict__ row_ptr,
                                              const int* __restrict__ slot,
                                              int* __restrict__ csr_src,
                                              const int* __restrict__ flags,
                                              int E, int N) {
  int e = blockIdx.x * 256 + threadIdx.x;
  if (e >= E) return;
  int i64 = flags[1];
  int src = clampN(ldi(pe, e, i64), N);
  int col = clampN(ldi(pe, (long long)E + e, i64), N);
  csr_src[row_ptr[col] + slot[e]] = src;
}

// --- gemm1 (MFMA): xw1 = x @ W1, bf16 out ----------------------------------
// wave: 16 rows x 64 cols. A[m=lane&15][k=quad*8+j]; C/D col=lane&15,
// row=quad*4+reg (verified m89).
__global__ __launch_bounds__(256) void k_gemm1(const void* __restrict__ x,
                                               const unsigned short* __restrict__ w1t,
                                               unsigned short* __restrict__ xw1,
                                               const int* __restrict__ flags, int N) {
  int w = threadIdx.x >> 6, lane = threadIdx.x & 63;
  int m = lane & 15, quad = lane >> 4;
  int r0 = blockIdx.x * 64 + w * 16;
  int rr = r0 + m; if (rr >= N) rr = N - 1;
  int f32 = flags[0];
  short8 A[4];
  if (f32) {
    const float* xf = (const float*)x + (size_t)rr * IN_F;
#pragma unroll
    for (int ks = 0; ks < 4; ++ks) {
      const float* p = xf + ks * 32 + quad * 8;
      short8 a;
#pragma unroll
      for (int j = 0; j < 8; ++j) a[j] = (short)f2bf(p[j]);
      A[ks] = a;
    }
  } else {
    const unsigned short* xb = (const unsigned short*)x + (size_t)rr * IN_F;
#pragma unroll
    for (int ks = 0; ks < 4; ++ks)
      A[ks] = *(const short8*)(xb + ks * 32 + quad * 8);
  }
#pragma unroll
  for (int nt = 0; nt < 4; ++nt) {
    f32x4 acc = {0.f, 0.f, 0.f, 0.f};
#pragma unroll
    for (int ks = 0; ks < 4; ++ks) {
      short8 Bf = *(const short8*)(w1t + (nt * 16 + m) * IN_F + ks * 32 + quad * 8);
      acc = __builtin_amdgcn_mfma_f32_16x16x32_bf16(A[ks], Bf, acc, 0, 0, 0);
    }
#pragma unroll
    for (int reg = 0; reg < 4; ++reg) {
      int row = r0 + quad * 4 + reg;
      if (row < N) xw1[(size_t)row * HID_F + nt * 16 + m] = f2bf(acc[reg]);
    }
  }
}

// --- gather1: h = relu(b1 + dv*(dv*xw1[v] + sum dinv[s]*xw1[s])), bf16 out -
__global__ __launch_bounds__(256) void k_gather1(const int* __restrict__ row_ptr,
                                                 const int* __restrict__ csr_src,
                                                 const float* __restrict__ dinv,
                                                 const unsigned short* __restrict__ xw1,
                                                 const void* __restrict__ b1,
                                                 unsigned short* __restrict__ h,
                                                 const int* __restrict__ flags, int N) {
  int v = blockIdx.x * 4 + (threadIdx.x >> 6);
  if (v >= N) return;
  int lane = threadIdx.x & 63;
  int sub = lane >> 3, l8 = lane & 7;
  int start = row_ptr[v], end = row_ptr[v + 1];
  float a[8] = {0.f,0.f,0.f,0.f,0.f,0.f,0.f,0.f};
  for (int j = start + sub; j < end; j += 8) {
    int s = csr_src[j];
    float ds = dinv[s];
    bfx8 wv = *(const bfx8*)(xw1 + (size_t)s * HID_F + l8 * 8);
#pragma unroll
    for (int q = 0; q < 8; ++q) a[q] += ds * bf2f(wv[q]);
  }
#pragma unroll
  for (int q = 0; q < 8; ++q) {
    a[q] += __shfl_xor(a[q], 8);
    a[q] += __shfl_xor(a[q], 16);
    a[q] += __shfl_xor(a[q], 32);
  }
  if (sub == 0) {
    float dv = dinv[v];
    bfx8 sw = *(const bfx8*)(xw1 + (size_t)v * HID_F + l8 * 8);
    int f32 = flags[0];
    bfx8 r;
#pragma unroll
    for (int q = 0; q < 8; ++q) {
      float val = ldf(b1, l8 * 8 + q, f32) + dv * (dv * bf2f(sw[q]) + a[q]);
      r[q] = f2bf(fmaxf(val, 0.f));
    }
    *(bfx8*)(h + (size_t)v * HID_F + l8 * 8) = r;
  }
}

// --- gemm2 (MFMA): xw2 = h @ W2, bf16 out ----------------------------------
__global__ __launch_bounds__(256) void k_gemm2(const unsigned short* __restrict__ h,
                                               const unsigned short* __restrict__ w2t,
                                               unsigned short* __restrict__ xw2, int N) {
  int w = threadIdx.x >> 6, lane = threadIdx.x & 63;
  int m = lane & 15, quad = lane >> 4;
  int r0 = blockIdx.x * 64 + w * 16;
  int rr = r0 + m; if (rr >= N) rr = N - 1;
  const unsigned short* hb = h + (size_t)rr * HID_F;
  short8 A[2];
#pragma unroll
  for (int ks = 0; ks < 2; ++ks)
    A[ks] = *(const short8*)(hb + ks * 32 + quad * 8);
#pragma unroll
  for (int nt = 0; nt < 2; ++nt) {
    f32x4 acc = {0.f, 0.f, 0.f, 0.f};
#pragma unroll
    for (int ks = 0; ks < 2; ++ks) {
      short8 Bf = *(const short8*)(w2t + (nt * 16 + m) * HID_F + ks * 32 + quad * 8);
      acc = __builtin_amdgcn_mfma_f32_16x16x32_bf16(A[ks], Bf, acc, 0, 0, 0);
    }
#pragma unroll
    for (int reg = 0; reg < 4; ++reg) {
      int row = r0 + quad * 4 + reg;
      if (row < N) xw2[(size_t)row * OUT_F + nt * 16 + m] = f2bf(acc[reg]);
    }
  }
}

// --- gather2: z = b2 + dv*(dv*xw2[v] + sum dinv[s]*xw2[s]), bf16 out -------
__global__ __launch_bounds__(256) void k_gather2(const int* __restrict__ row_ptr,
                                                 const int* __restrict__ csr_src,
                                                 const float* __restrict__ dinv,
                                                 const unsigned short* __restrict__ xw2,
                                                 const void* __restrict__ b2,
                                                 unsigned short* __restrict__ z,
                                                 const int* __restrict__ flags, int N) {
  int v = blockIdx.x * 4 + (threadIdx.x >> 6);
  if (v >= N) return;
  int lane = threadIdx.x & 63;
  int sub = lane >> 3, l8 = lane & 7;
  int start = row_ptr[v], end = row_ptr[v + 1];
  float a[4] = {0.f, 0.f, 0.f, 0.f};
  for (int j = start + sub; j < end; j += 8) {
    int s = csr_src[j];
    float ds = dinv[s];
    bfx4 wv = *(const bfx4*)(xw2 + (size_t)s * OUT_F + l8 * 4);
#pragma unroll
    for (int q = 0; q < 4; ++q) a[q] += ds * bf2f(wv[q]);
  }
#pragma unroll
  for (int q = 0; q < 4; ++q) {
    a[q] += __shfl_xor(a[q], 8);
    a[q] += __shfl_xor(a[q], 16);
    a[q] += __shfl_xor(a[q], 32);
  }
  if (sub == 0) {
    float dv = dinv[v];
    bfx4 sw = *(const bfx4*)(xw2 + (size_t)v * OUT_F + l8 * 4);
    int f32 = flags[0];
    bfx4 r;
#pragma unroll
    for (int q = 0; q < 4; ++q)
      r[q] = f2bf(ldf(b2, l8 * 4 + q, f32) + dv * (dv * bf2f(sw[q]) + a[q]));
    *(bfx4*)(z + (size_t)v * OUT_F + l8 * 4) = r;
  }
}

// --- decode + edge copy: 4 lanes/edge, bf16 z, f32 accumulate --------------
__global__ __launch_bounds__(256) void k_decode(const void* __restrict__ pe,
                                                const void* __restrict__ ne,
                                                const unsigned short* __restrict__ z,
                                                float* __restrict__ out,
                                                const int* __restrict__ flags,
                                                int E, int N) {
  int tid = blockIdx.x * 256 + threadIdx.x;
  int e = tid >> 2, g = tid & 3;
  int twoE = 2 * E;
  if (e >= twoE) return;
  int i64 = flags[1];
  int src, dst;
  if (e < E) { src = ldi(pe, e, i64); dst = ldi(pe, (long long)E + e, i64); }
  else       { src = ldi(ne, e - E, i64); dst = ldi(ne, e, i64); }
  if (g == 1) out[twoE + e] = (float)src;        // edge row0 passthrough
  if (g == 2) out[2 * twoE + e] = (float)dst;    // edge row1 passthrough
  int cs = clampN(src, N), cd = clampN(dst, N);
  bfx8 a = *(const bfx8*)(z + (size_t)cs * OUT_F + g * 8);
  bfx8 b = *(const bfx8*)(z + (size_t)cd * OUT_F + g * 8);
  float s = 0.f;
#pragma unroll
  for (int q = 0; q < 8; ++q) s += bf2f(a[q]) * bf2f(b[q]);
  s += __shfl_xor(s, 1);
  s += __shfl_xor(s, 2);
  s = fminf(fmaxf(s, -500.0f), 500.0f);          // insurance rail (R2 notes)
  if (g == 0) out[e] = s;
}

extern "C" void kernel_launch(void* const* d_in, const int* in_sizes, int n_in,
                              void* d_out, int out_size, void* d_ws, size_t ws_size,
                              hipStream_t stream) {
  const void* x  = d_in[0];
  const void* W1 = d_in[1];
  const void* b1 = d_in[2];
  const void* W2 = d_in[3];
  const void* b2 = d_in[4];
  const void* pe = d_in[5];
  const void* ne = d_in[6];
  int N = in_sizes[0] / IN_F;       // 100000
  int E = in_sizes[5] / 2;          // 1600000
  int B = (N + 1023) / 1024;        // 98

  int*   ip    = (int*)d_ws;
  float* ws    = (float*)d_ws;
  int*   cnt   = ip + OFF_CNT;
  int*   flags = ip + OFF_FLAGS;
  int*   bsums = ip + OFF_BSUMS;
  unsigned short* w1t = (unsigned short*)(ip + OFF_W1T);
  unsigned short* w2t = (unsigned short*)(ip + OFF_W2T);
  int*   rowp  = ip + OFF_ROWP;
  float* dinv  = ws + OFF_DINV;
  int*   slot  = ip + OFF_SLOT;
  int*   csr   = ip + OFF_CSR;
  unsigned short* xw1 = (unsigned short*)(ip + OFF_XW1);
  unsigned short* h   = (unsigned short*)(ip + OFF_H);
  unsigned short* xw2 = (unsigned short*)(ip + OFF_XW2);
  unsigned short* zz  = (unsigned short*)(ip + OFF_Z);
  float* out   = (float*)d_out;

  k_prep<<<1 + (N + 255) / 256, 256, 0, stream>>>(x, pe, W1, W2, flags, w1t, w2t, cnt, N);
  k_countslot<<<(E + 255) / 256, 256, 0, stream>>>(pe, cnt, slot, flags, E, N);
  k_bsum<<<B, 256, 0, stream>>>(cnt, bsums, N);
  k_scan_bsums<<<1, 64, 0, stream>>>(bsums, B);
  k_scan_apply<<<B, 256, 0, stream>>>(cnt, bsums, rowp, dinv, N, B);
  k_fill<<<(E + 255) / 256, 256, 0, stream>>>(pe, rowp, slot, csr, flags, E, N);
  k_gemm1<<<(N + 63) / 64, 256, 0, stream>>>(x, w1t, xw1, flags, N);
  k_gather1<<<(N + 3) / 4, 256, 0, stream>>>(rowp, csr, dinv, xw1, b1, h, flags, N);
  k_gemm2<<<(N + 63) / 64, 256, 0, stream>>>(h, w2t, xw2, N);
  k_gather2<<<(N + 3) / 4, 256, 0, stream>>>(rowp, csr, dinv, xw2, b2, zz, flags, N);
  k_decode<<<(2 * E * 4 + 255) / 256, 256, 0, stream>>>(pe, ne, zz, out, flags, E, N);
}

// Round 8
// 387.570 us; speedup vs baseline: 3.3704x; 1.0986x over previous
//
#include <hip/hip_runtime.h>
#include <hip/hip_bf16.h>

// ---------------------------------------------------------------------------
// GCN link predictor, R8: atomic-free CSR build (bucket radix) + bf16 z.
// R7 post-mortem: countslot 67us — 1.6M returning global atomics write
// ~50MB through to HBM (32B/atomic sector); fill pays similar for random 4B
// stores. Replacement: LDS-histogram bucket radix (hist -> colscan ->
// scatter -> bucket counting-sort). ALL atomics are LDS; all global writes
// coalesced or confined to per-bucket L2-resident windows. (R6 lesson:
// global same-address atomics serialize ~110ns each — zero of them here.)
//   h = relu(b1 + dv*(dv*xw1[v] + sum dinv[s]*xw1[s])),  xw1 = x @ W1 (MFMA)
//   z = b2 + dv*(dv*xw2[v] + sum dinv[s]*xw2[s]),        xw2 = h @ W2 (MFMA)
//   logits[e] = dot(z[src], z[dst]) over [pos; neg]
// Output: FLOAT32 [logits(2E)][edge row0(2E)][row1(2E)] (established R2).
// ---------------------------------------------------------------------------

#define IN_F  128
#define HID_F 64
#define OUT_F 32
#define NA    200      // edge-chunk blocks for hist/scatter
#define NBS   512      // histogram stride (>= NB=391 buckets of 256 nodes)

// workspace element offsets (4-byte units); N=100000, E=1600000; 58.8 MB
#define OFF_FLAGS   0          // 2 ints
#define OFF_W1T     64         // 8192 bf16 = 4096 ints
#define OFF_W2T     4160       // 2048 bf16 = 1024 ints
#define OFF_HIST    5200       // NA*NBS = 102400 ints
#define OFF_BTOT    107600     // 512 ints
#define OFF_ROWP    108200     // N+1 ints
#define OFF_DINV    208300     // N floats
#define OFF_EPAIRS  308300     // 2E ints (int2 pairs; byte-offset % 8 == 0)
#define OFF_CSR     3508300    // E ints
#define OFF_XW1     5108300    // N*64 bf16 = 3.2M ints
#define OFF_H       8308300    // N*64 bf16
#define OFF_XW2     11508300   // N*32 bf16 = 1.6M ints
#define OFF_Z       13108300   // N*32 bf16 -> end 14708300

typedef short short8 __attribute__((ext_vector_type(8)));
typedef float f32x4  __attribute__((ext_vector_type(4)));
typedef unsigned short bfx8 __attribute__((ext_vector_type(8)));
typedef unsigned short bfx4 __attribute__((ext_vector_type(4)));

__device__ __forceinline__ float ldf(const void* p, int i, int f32) {
  if (f32) return ((const float*)p)[i];
  unsigned int w = ((unsigned int)((const unsigned short*)p)[i]) << 16;
  return __uint_as_float(w);
}
__device__ __forceinline__ int ldi(const void* p, long long i, int i64) {
  if (i64) return (int)((const long long*)p)[i];
  return ((const int*)p)[i];
}
__device__ __forceinline__ int clampN(int v, int N) {
  unsigned u = (unsigned)v;
  return (u < (unsigned)N) ? v : 0;
}
__device__ __forceinline__ unsigned short f2bf(float f) {   // RNE f32->bf16
  unsigned u = __float_as_uint(f);
  return (unsigned short)((u + 0x7FFFu + ((u >> 16) & 1u)) >> 16);
}
__device__ __forceinline__ float bf2f(unsigned short h) {
  return __uint_as_float(((unsigned)h) << 16);
}

// --- prep (grid 1): detect dtypes + transpose weights ----------------------
__global__ __launch_bounds__(256) void k_prep(const void* __restrict__ x,
                                              const void* __restrict__ pe,
                                              const void* __restrict__ W1,
                                              const void* __restrict__ W2,
                                              int* __restrict__ flags,
                                              unsigned short* __restrict__ w1t,
                                              unsigned short* __restrict__ w2t) {
  __shared__ int s_big, s_nzodd;
  int t = threadIdx.x;
  if (t == 0) { s_big = 0; s_nzodd = 0; }
  __syncthreads();
  int nbig = 0, nz = 0;
  const unsigned short* xb = (const unsigned short*)x;
  for (int i = t; i < 4096; i += 256) {
    int ex = (xb[i] >> 7) & 0xFF;
    if (ex >= 147) nbig++;               // |v|>=2^20 impossible for N(0,1) bf16
  }
  const int* pi = (const int*)pe;
  for (int i = t; i < 2048; i += 256) {
    if (pi[2 * i + 1] != 0) nz++;        // int64 hi-words all zero
  }
  atomicAdd(&s_big, nbig);
  atomicAdd(&s_nzodd, nz);
  __syncthreads();
  int f32 = (s_big > 400) ? 1 : 0;
  if (t == 0) {
    flags[0] = f32;
    flags[1] = (s_nzodd < 100) ? 1 : 0;
  }
  for (int i = t; i < HID_F * IN_F; i += 256) {   // W1T[n*128+k] = W1[k*64+n]
    int n = i >> 7, k = i & 127;
    w1t[i] = f2bf(ldf(W1, k * HID_F + n, f32));
  }
  for (int i = t; i < OUT_F * HID_F; i += 256) {  // W2T[n*64+k] = W2[k*32+n]
    int n = i >> 6, k = i & 63;
    w2t[i] = f2bf(ldf(W2, k * OUT_F + n, f32));
  }
}

// --- CSR build pass 1: per-chunk LDS histogram over buckets ---------------
__global__ __launch_bounds__(256) void k_hist(const void* __restrict__ pe,
                                              int* __restrict__ histmat,
                                              const int* __restrict__ flags,
                                              int E, int N, int CH) {
  __shared__ int hist[NBS];
  int t = threadIdx.x;
  for (int i = t; i < NBS; i += 256) hist[i] = 0;
  __syncthreads();
  int i64 = flags[1];
  int base = blockIdx.x * CH, end = min(base + CH, E);
  for (int e = base + t; e < end; e += 256) {
    int dst = clampN(ldi(pe, (long long)E + e, i64), N);
    atomicAdd(&hist[dst >> 8], 1);       // LDS atomic
  }
  __syncthreads();
  for (int i = t; i < NBS; i += 256) histmat[blockIdx.x * NBS + i] = hist[i];
}

// --- pass 2: per-bucket column exclusive scan + bucket totals --------------
__global__ __launch_bounds__(256) void k_colscan(int* __restrict__ histmat,
                                                 int* __restrict__ btot) {
  __shared__ int a[256];
  int b = blockIdx.x, t = threadIdx.x;
  int h = (t < NA) ? histmat[t * NBS + b] : 0;
  a[t] = h;
  __syncthreads();
  for (int off = 1; off < 256; off <<= 1) {
    int v = (t >= off) ? a[t - off] : 0;
    __syncthreads();
    a[t] += v;
    __syncthreads();
  }
  if (t < NA) histmat[t * NBS + b] = a[t] - h;   // exclusive within column
  if (t == 255) btot[b] = a[255];
}

// --- pass 3: scatter pairs into bucket-sorted order (LDS cursors only) -----
__global__ __launch_bounds__(256) void k_scatter(const void* __restrict__ pe,
                                                 const int* __restrict__ histmat,
                                                 const int* __restrict__ btot,
                                                 int2* __restrict__ epairs,
                                                 const int* __restrict__ flags,
                                                 int E, int N, int NB, int CH) {
  __shared__ int sc[NBS];
  __shared__ int cur[NBS];
  int t = threadIdx.x;
  int o0 = (t < NB) ? btot[t] : 0;
  int o1 = (t + 256 < NB) ? btot[t + 256] : 0;
  sc[t] = o0; sc[t + 256] = o1;
  __syncthreads();
  for (int off = 1; off < NBS; off <<= 1) {      // Hillis-Steele, 2 slots/thread
    int v0 = (t >= off) ? sc[t - off] : 0;
    int v1 = (t + 256 >= off) ? sc[t + 256 - off] : 0;
    __syncthreads();
    sc[t] += v0; sc[t + 256] += v1;
    __syncthreads();
  }
  const int* row = histmat + blockIdx.x * NBS;   // contiguous row
  cur[t]       = sc[t] - o0 + row[t];            // bucket base + block cursor
  cur[t + 256] = sc[t + 256] - o1 + row[t + 256];
  __syncthreads();
  int i64 = flags[1];
  int base = blockIdx.x * CH, end = min(base + CH, E);
  for (int e = base + t; e < end; e += 256) {
    int src = clampN(ldi(pe, e, i64), N);
    int dst = clampN(ldi(pe, (long long)E + e, i64), N);
    int pos = atomicAdd(&cur[dst >> 8], 1);      // LDS atomic
    epairs[pos] = make_int2(src, dst);
  }
}

// --- pass 4: per-bucket counting sort -> csr; emits rowp + dinv ------------
__global__ __launch_bounds__(256) void k_bsort(const int2* __restrict__ epairs,
                                               const int* __restrict__ btot,
                                               int* __restrict__ rowp,
                                               float* __restrict__ dinv,
                                               int* __restrict__ csr,
                                               int N, int NB) {
  __shared__ int red[256];
  __shared__ int cnt[256];
  __shared__ int cur2[256];
  __shared__ int s_start;
  int b = blockIdx.x, t = threadIdx.x;
  int acc = 0;
  for (int i = t; i < b; i += 256) acc += btot[i];   // bstart = sum btot[<b]
  red[t] = acc;
  __syncthreads();
  for (int off = 128; off > 0; off >>= 1) {
    if (t < off) red[t] += red[t + off];
    __syncthreads();
  }
  if (t == 0) s_start = red[0];
  __syncthreads();
  int bstart = s_start, bend = bstart + btot[b];
  int node0 = b << 8, nn = min(N - node0, 256);
  cnt[t] = 0;
  __syncthreads();
  for (int j = bstart + t; j < bend; j += 256)
    atomicAdd(&cnt[epairs[j].y - node0], 1);         // LDS atomic
  __syncthreads();
  int c = cnt[t];
  red[t] = c;
  __syncthreads();
  for (int off = 1; off < 256; off <<= 1) {          // inclusive scan
    int v = (t >= off) ? red[t - off] : 0;
    __syncthreads();
    red[t] += v;
    __syncthreads();
  }
  int excl = red[t] - c;
  if (t < nn) {
    rowp[node0 + t] = bstart + excl;
    dinv[node0 + t] = 1.0f / sqrtf((float)(c + 1));  // +1 self loop
    cur2[t] = bstart + excl;
  }
  __syncthreads();
  for (int j = bstart + t; j < bend; j += 256) {
    int2 p = epairs[j];
    int pos = atomicAdd(&cur2[p.y - node0], 1);      // LDS atomic
    csr[pos] = p.x;                                  // ~16KB window: L2-local
  }
  if (b == NB - 1 && t == 0) rowp[N] = bend;
}

// --- gemm1 (MFMA): xw1 = x @ W1, bf16 out ----------------------------------
__global__ __launch_bounds__(256) void k_gemm1(const void* __restrict__ x,
                                               const unsigned short* __restrict__ w1t,
                                               unsigned short* __restrict__ xw1,
                                               const int* __restrict__ flags, int N) {
  int w = threadIdx.x >> 6, lane = threadIdx.x & 63;
  int m = lane & 15, quad = lane >> 4;
  int r0 = blockIdx.x * 64 + w * 16;
  int rr = r0 + m; if (rr >= N) rr = N - 1;
  int f32 = flags[0];
  short8 A[4];
  if (f32) {
    const float* xf = (const float*)x + (size_t)rr * IN_F;
#pragma unroll
    for (int ks = 0; ks < 4; ++ks) {
      const float* p = xf + ks * 32 + quad * 8;
      short8 a;
#pragma unroll
      for (int j = 0; j < 8; ++j) a[j] = (short)f2bf(p[j]);
      A[ks] = a;
    }
  } else {
    const unsigned short* xb = (const unsigned short*)x + (size_t)rr * IN_F;
#pragma unroll
    for (int ks = 0; ks < 4; ++ks)
      A[ks] = *(const short8*)(xb + ks * 32 + quad * 8);
  }
#pragma unroll
  for (int nt = 0; nt < 4; ++nt) {
    f32x4 acc = {0.f, 0.f, 0.f, 0.f};
#pragma unroll
    for (int ks = 0; ks < 4; ++ks) {
      short8 Bf = *(const short8*)(w1t + (nt * 16 + m) * IN_F + ks * 32 + quad * 8);
      acc = __builtin_amdgcn_mfma_f32_16x16x32_bf16(A[ks], Bf, acc, 0, 0, 0);
    }
#pragma unroll
    for (int reg = 0; reg < 4; ++reg) {
      int row = r0 + quad * 4 + reg;
      if (row < N) xw1[(size_t)row * HID_F + nt * 16 + m] = f2bf(acc[reg]);
    }
  }
}

// --- gather1: h = relu(b1 + dv*(dv*xw1[v] + sum dinv[s]*xw1[s])), bf16 out -
__global__ __launch_bounds__(256) void k_gather1(const int* __restrict__ row_ptr,
                                                 const int* __restrict__ csr_src,
                                                 const float* __restrict__ dinv,
                                                 const unsigned short* __restrict__ xw1,
                                                 const void* __restrict__ b1,
                                                 unsigned short* __restrict__ h,
                                                 const int* __restrict__ flags, int N) {
  int v = blockIdx.x * 4 + (threadIdx.x >> 6);
  if (v >= N) return;
  int lane = threadIdx.x & 63;
  int sub = lane >> 3, l8 = lane & 7;
  int start = row_ptr[v], end = row_ptr[v + 1];
  float a[8] = {0.f,0.f,0.f,0.f,0.f,0.f,0.f,0.f};
  for (int j = start + sub; j < end; j += 8) {
    int s = csr_src[j];
    float ds = dinv[s];
    bfx8 wv = *(const bfx8*)(xw1 + (size_t)s * HID_F + l8 * 8);
#pragma unroll
    for (int q = 0; q < 8; ++q) a[q] += ds * bf2f(wv[q]);
  }
#pragma unroll
  for (int q = 0; q < 8; ++q) {
    a[q] += __shfl_xor(a[q], 8);
    a[q] += __shfl_xor(a[q], 16);
    a[q] += __shfl_xor(a[q], 32);
  }
  if (sub == 0) {
    float dv = dinv[v];
    bfx8 sw = *(const bfx8*)(xw1 + (size_t)v * HID_F + l8 * 8);
    int f32 = flags[0];
    bfx8 r;
#pragma unroll
    for (int q = 0; q < 8; ++q) {
      float val = ldf(b1, l8 * 8 + q, f32) + dv * (dv * bf2f(sw[q]) + a[q]);
      r[q] = f2bf(fmaxf(val, 0.f));
    }
    *(bfx8*)(h + (size_t)v * HID_F + l8 * 8) = r;
  }
}

// --- gemm2 (MFMA): xw2 = h @ W2, bf16 out ----------------------------------
__global__ __launch_bounds__(256) void k_gemm2(const unsigned short* __restrict__ h,
                                               const unsigned short* __restrict__ w2t,
                                               unsigned short* __restrict__ xw2, int N) {
  int w = threadIdx.x >> 6, lane = threadIdx.x & 63;
  int m = lane & 15, quad = lane >> 4;
  int r0 = blockIdx.x * 64 + w * 16;
  int rr = r0 + m; if (rr >= N) rr = N - 1;
  const unsigned short* hb = h + (size_t)rr * HID_F;
  short8 A[2];
#pragma unroll
  for (int ks = 0; ks < 2; ++ks)
    A[ks] = *(const short8*)(hb + ks * 32 + quad * 8);
#pragma unroll
  for (int nt = 0; nt < 2; ++nt) {
    f32x4 acc = {0.f, 0.f, 0.f, 0.f};
#pragma unroll
    for (int ks = 0; ks < 2; ++ks) {
      short8 Bf = *(const short8*)(w2t + (nt * 16 + m) * HID_F + ks * 32 + quad * 8);
      acc = __builtin_amdgcn_mfma_f32_16x16x32_bf16(A[ks], Bf, acc, 0, 0, 0);
    }
#pragma unroll
    for (int reg = 0; reg < 4; ++reg) {
      int row = r0 + quad * 4 + reg;
      if (row < N) xw2[(size_t)row * OUT_F + nt * 16 + m] = f2bf(acc[reg]);
    }
  }
}

// --- gather2: z = b2 + dv*(dv*xw2[v] + sum dinv[s]*xw2[s]), bf16 out -------
__global__ __launch_bounds__(256) void k_gather2(const int* __restrict__ row_ptr,
                                                 const int* __restrict__ csr_src,
                                                 const float* __restrict__ dinv,
                                                 const unsigned short* __restrict__ xw2,
                                                 const void* __restrict__ b2,
                                                 unsigned short* __restrict__ z,
                                                 const int* __restrict__ flags, int N) {
  int v = blockIdx.x * 4 + (threadIdx.x >> 6);
  if (v >= N) return;
  int lane = threadIdx.x & 63;
  int sub = lane >> 3, l8 = lane & 7;
  int start = row_ptr[v], end = row_ptr[v + 1];
  float a[4] = {0.f, 0.f, 0.f, 0.f};
  for (int j = start + sub; j < end; j += 8) {
    int s = csr_src[j];
    float ds = dinv[s];
    bfx4 wv = *(const bfx4*)(xw2 + (size_t)s * OUT_F + l8 * 4);
#pragma unroll
    for (int q = 0; q < 4; ++q) a[q] += ds * bf2f(wv[q]);
  }
#pragma unroll
  for (int q = 0; q < 4; ++q) {
    a[q] += __shfl_xor(a[q], 8);
    a[q] += __shfl_xor(a[q], 16);
    a[q] += __shfl_xor(a[q], 32);
  }
  if (sub == 0) {
    float dv = dinv[v];
    bfx4 sw = *(const bfx4*)(xw2 + (size_t)v * OUT_F + l8 * 4);
    int f32 = flags[0];
    bfx4 r;
#pragma unroll
    for (int q = 0; q < 4; ++q)
      r[q] = f2bf(ldf(b2, l8 * 4 + q, f32) + dv * (dv * bf2f(sw[q]) + a[q]));
    *(bfx4*)(z + (size_t)v * OUT_F + l8 * 4) = r;
  }
}

// --- decode + edge copy: 4 lanes/edge, bf16 z, f32 accumulate --------------
__global__ __launch_bounds__(256) void k_decode(const void* __restrict__ pe,
                                                const void* __restrict__ ne,
                                                const unsigned short* __restrict__ z,
                                                float* __restrict__ out,
                                                const int* __restrict__ flags,
                                                int E, int N) {
  int tid = blockIdx.x * 256 + threadIdx.x;
  int e = tid >> 2, g = tid & 3;
  int twoE = 2 * E;
  if (e >= twoE) return;
  int i64 = flags[1];
  int src, dst;
  if (e < E) { src = ldi(pe, e, i64); dst = ldi(pe, (long long)E + e, i64); }
  else       { src = ldi(ne, e - E, i64); dst = ldi(ne, e, i64); }
  if (g == 1) out[twoE + e] = (float)src;        // edge row0 passthrough
  if (g == 2) out[2 * twoE + e] = (float)dst;    // edge row1 passthrough
  int cs = clampN(src, N), cd = clampN(dst, N);
  bfx8 a = *(const bfx8*)(z + (size_t)cs * OUT_F + g * 8);
  bfx8 b = *(const bfx8*)(z + (size_t)cd * OUT_F + g * 8);
  float s = 0.f;
#pragma unroll
  for (int q = 0; q < 8; ++q) s += bf2f(a[q]) * bf2f(b[q]);
  s += __shfl_xor(s, 1);
  s += __shfl_xor(s, 2);
  s = fminf(fmaxf(s, -500.0f), 500.0f);          // insurance rail (R2 notes)
  if (g == 0) out[e] = s;
}

extern "C" void kernel_launch(void* const* d_in, const int* in_sizes, int n_in,
                              void* d_out, int out_size, void* d_ws, size_t ws_size,
                              hipStream_t stream) {
  const void* x  = d_in[0];
  const void* W1 = d_in[1];
  const void* b1 = d_in[2];
  const void* W2 = d_in[3];
  const void* b2 = d_in[4];
  const void* pe = d_in[5];
  const void* ne = d_in[6];
  int N = in_sizes[0] / IN_F;       // 100000
  int E = in_sizes[5] / 2;          // 1600000
  int NB = (N + 255) >> 8;          // 391 buckets
  int CH = (E + NA - 1) / NA;       // 8000 edges/chunk

  int*   ip    = (int*)d_ws;
  float* ws    = (float*)d_ws;
  int*   flags = ip + OFF_FLAGS;
  unsigned short* w1t = (unsigned short*)(ip + OFF_W1T);
  unsigned short* w2t = (unsigned short*)(ip + OFF_W2T);
  int*   hist  = ip + OFF_HIST;
  int*   btot  = ip + OFF_BTOT;
  int*   rowp  = ip + OFF_ROWP;
  float* dinv  = ws + OFF_DINV;
  int2*  epairs= (int2*)(ip + OFF_EPAIRS);
  int*   csr   = ip + OFF_CSR;
  unsigned short* xw1 = (unsigned short*)(ip + OFF_XW1);
  unsigned short* h   = (unsigned short*)(ip + OFF_H);
  unsigned short* xw2 = (unsigned short*)(ip + OFF_XW2);
  unsigned short* zz  = (unsigned short*)(ip + OFF_Z);
  float* out   = (float*)d_out;

  k_prep<<<1, 256, 0, stream>>>(x, pe, W1, W2, flags, w1t, w2t);
  k_hist<<<NA, 256, 0, stream>>>(pe, hist, flags, E, N, CH);
  k_colscan<<<NB, 256, 0, stream>>>(hist, btot);
  k_scatter<<<NA, 256, 0, stream>>>(pe, hist, btot, epairs, flags, E, N, NB, CH);
  k_bsort<<<NB, 256, 0, stream>>>(epairs, btot, rowp, dinv, csr, N, NB);
  k_gemm1<<<(N + 63) / 64, 256, 0, stream>>>(x, w1t, xw1, flags, N);
  k_gather1<<<(N + 3) / 4, 256, 0, stream>>>(rowp, csr, dinv, xw1, b1, h, flags, N);
  k_gemm2<<<(N + 63) / 64, 256, 0, stream>>>(h, w2t, xw2, N);
  k_gather2<<<(N + 3) / 4, 256, 0, stream>>>(rowp, csr, dinv, xw2, b2, zz, flags, N);
  k_decode<<<(2 * E * 4 + 255) / 256, 256, 0, stream>>>(pe, ne, zz, out, flags, E, N);
}